// Round 7
// baseline (277.627 us; speedup 1.0000x reference)
//
#include <hip/hip_runtime.h>
#include <hip/hip_bf16.h>
#include <stdint.h>

#define B_ROWS 32768
#define DIM 512
#define THREADS 512
#define NKT 16              // K-steps of 64 over K=1024
#define ABUF 16384          // 128 rows x 128 B
#define WBUF 24576          // 3 mats x 64 cols x 128 B
#define BUF (ABUF + WBUF)   // 40 KB per stage; x2 = 80 KB -> 2 blocks/CU (160 KiB)

typedef __attribute__((ext_vector_type(8))) __bf16 bf16x8;
typedef __attribute__((ext_vector_type(4))) float f32x4;
typedef __attribute__((ext_vector_type(4))) unsigned int uint4v;

__device__ static inline unsigned short f2bf(float f) {
    unsigned int u = __builtin_bit_cast(unsigned int, f);
    u += 0x7fffu + ((u >> 16) & 1u);
    return (unsigned short)(u >> 16);
}

__device__ static inline void load_lds_16B(const void* g, void* lds) {
    __builtin_amdgcn_global_load_lds(
        (const __attribute__((address_space(1))) unsigned int*)g,
        (__attribute__((address_space(3))) unsigned int*)lds,
        16, 0, 0);
}

// Wt2[kt 0..15][t 0..2][n 0..511][128B]: element (t,n,k): kt=k>>6, kk=k&63,
// byte = (kk*2) ^ ((n&7)<<4).
__global__ void prep_weights(const float* __restrict__ Wu_x, const float* __restrict__ Wu_h,
                             const float* __restrict__ Wr_x, const float* __restrict__ Wr_h,
                             const float* __restrict__ Wc_x, const float* __restrict__ Wc_h,
                             unsigned short* __restrict__ Wt2) {
    __shared__ float tile[32][33];
    const int t = blockIdx.z;
    const int k0 = blockIdx.x * 32;
    const int n0 = blockIdx.y * 32;
    const float* Wx = (t == 0) ? Wu_x : (t == 1) ? Wr_x : Wc_x;
    const float* Wh = (t == 0) ? Wu_h : (t == 1) ? Wr_h : Wc_h;
    const int tid = threadIdx.x;
    const int c = tid & 31, r0 = tid >> 5;
#pragma unroll
    for (int i = 0; i < 4; ++i) {
        int kl = r0 + i * 8;
        int k = k0 + kl;
        int n = n0 + c;
        float v = (k < 512) ? Wx[(size_t)k * 512 + n] : Wh[(size_t)(k - 512) * 512 + n];
        tile[kl][c] = v;
    }
    __syncthreads();
    const int kt = k0 >> 6;
    const int kkb = k0 & 32;
#pragma unroll
    for (int i = 0; i < 4; ++i) {
        int nl = r0 + i * 8;
        int kc = c;
        int n = n0 + nl;
        size_t base = (((size_t)kt * 3 + t) * 512 + n) * 128;
        *(unsigned short*)((char*)Wt2 + base + (((kkb + kc) * 2) ^ ((n & 7) << 4))) =
            f2bf(tile[kc][nl]);
    }
}

// Apack[kt 0..15][row 0..32767][128B]: 16B slot s (0..7) of row r at byte
// (s*16) ^ ((r&7)<<4). k = kt*64 + s*8 + e; k<512 from x else from h.
__global__ __launch_bounds__(512) void prep_A(const float* __restrict__ x,
                                              const float* __restrict__ h,
                                              unsigned short* __restrict__ Apack) {
    const size_t i = (size_t)blockIdx.x * 512 + threadIdx.x;  // 16B chunk id (4M)
    const int s = (int)(i & 7);
    const int row = (int)((i >> 3) & 32767);
    const int kt = (int)(i >> 18);
    const int k0 = kt * 64 + s * 8;   // 0..1016
    const float* src = (k0 < 512) ? (x + (size_t)row * 512 + k0)
                                  : (h + (size_t)row * 512 + (k0 - 512));
    float4 f0 = *(const float4*)(src + 0);
    float4 f1 = *(const float4*)(src + 4);
    uint4v p;
    p.x = f2bf(f0.x) | ((unsigned)f2bf(f0.y) << 16);
    p.y = f2bf(f0.z) | ((unsigned)f2bf(f0.w) << 16);
    p.z = f2bf(f1.x) | ((unsigned)f2bf(f1.y) << 16);
    p.w = f2bf(f1.z) | ((unsigned)f2bf(f1.w) << 16);
    char* dst = (char*)Apack + (((size_t)kt * 32768 + row) * 128)
              + ((s * 16) ^ ((row & 7) << 4));
    *(uint4v*)dst = p;
}

// ---- main: BM=128 BN=64 BK=64, 2x40KB dbuf, 2 blocks/CU, hoisted addressing ---
__global__ __launch_bounds__(THREADS, 4) void augru_main(
    const float* __restrict__ h, const float* __restrict__ att,
    const unsigned short* __restrict__ Wt2, const unsigned short* __restrict__ Apack,
    const float* __restrict__ bu, const float* __restrict__ br,
    const float* __restrict__ bc, float* __restrict__ out) {
    extern __shared__ char smem[];   // 2 x 40 KB
    const int tid = threadIdx.x;
    const int lane = tid & 63;
    const int wid = tid >> 6;
    const int wm = wid >> 2;   // 0..1 -> 64-row half
    const int wn = wid & 3;    // 0..3 -> 16-col slice
    const int id = blockIdx.x;
    const int wg = (id & 7) * 256 + (id >> 3);   // XCD-bijective (2048%8==0)
    const int nb = wg & 7;     // 0..7 -> 64-col block
    const int mb = wg >> 3;    // 0..255
    const int cl = lane & 15;
    const int kg = lane >> 4;

    f32x4 accU[4], accR[4], accCx[4], accCh[4];
#pragma unroll
    for (int i = 0; i < 4; ++i) {
        accU[i] = (f32x4)(0.f);
        accR[i] = (f32x4)(0.f);
        accCx[i] = (f32x4)(0.f);
        accCh[i] = (f32x4)(0.f);
    }

    // hoisted ds_read byte offsets ((cl&7)<<4 swizzle is mi/ks-invariant)
    const int swz = (cl & 7) << 4;
    int aOff[2][4], wOff[2][3];
#pragma unroll
    for (int ks = 0; ks < 2; ++ks) {
        const int kbyte = ks * 64 + kg * 16;
#pragma unroll
        for (int mi = 0; mi < 4; ++mi)
            aOff[ks][mi] = (wm * 64 + mi * 16 + cl) * 128 + (kbyte ^ swz);
#pragma unroll
        for (int t = 0; t < 3; ++t)
            wOff[ks][t] = ABUF + t * 8192 + (wn * 16 + cl) * 128 + (kbyte ^ swz);
    }

    // Staging: waves 0-3 carry W (6 loads), waves 4-7 carry A (4 loads).
    const char* gWbase = (const char*)Wt2 + (size_t)nb * 8192;
    const char* gAbase = (const char*)Apack + (size_t)mb * 128 * 128;
    auto stage = [&](int buf, int kt) {
        char* base = smem + buf * BUF;
        if (wid < 4) {
            const char* gW = gWbase + (size_t)kt * (3 * 512 * 128);
#pragma unroll
            for (int q = 0; q < 6; ++q) {
                const int b = wid * 6144 + q * 1024 + lane * 16;
                const int t = b >> 13;                // wave-uniform per q
                load_lds_16B(gW + t * 57344 + b, base + ABUF + (b & ~1023));
            }
        } else {
            const char* gA = gAbase + (size_t)kt * (32768 * 128);
#pragma unroll
            for (int q = 0; q < 4; ++q) {
                const int b = (wid - 4) * 4096 + q * 1024 + lane * 16;
                load_lds_16B(gA + b, base + (b & ~1023));
            }
        }
    };
    // note: W region per (kt): 3*512*128; t-block stride within = 512*128 = 65536;
    // linear b already includes t*8192 (nb slice), so add t*(65536-8192)=t*57344.

    stage(0, 0);

    auto body = [&](int kt, int buf, f32x4(&accC)[4]) {
        asm volatile("s_waitcnt vmcnt(0)" ::: "memory");  // stage(kt) landed;
                                                          // ~1 full iter of flight
        __builtin_amdgcn_s_barrier();                     // all waves done w/ buf^1
        if (kt + 1 < NKT) stage(buf ^ 1, kt + 1);
        const char* aB = smem + buf * BUF;
#pragma unroll
        for (int ks = 0; ks < 2; ++ks) {
            bf16x8 a[4], bb[3];
#pragma unroll
            for (int mi = 0; mi < 4; ++mi)
                a[mi] = __builtin_bit_cast(bf16x8, *(const uint4v*)(aB + aOff[ks][mi]));
#pragma unroll
            for (int t = 0; t < 3; ++t)
                bb[t] = __builtin_bit_cast(bf16x8, *(const uint4v*)(aB + wOff[ks][t]));
            __builtin_amdgcn_s_setprio(1);
#pragma unroll
            for (int mi = 0; mi < 4; ++mi)
                accU[mi] = __builtin_amdgcn_mfma_f32_16x16x32_bf16(
                    a[mi], bb[0], accU[mi], 0, 0, 0);
#pragma unroll
            for (int mi = 0; mi < 4; ++mi)
                accR[mi] = __builtin_amdgcn_mfma_f32_16x16x32_bf16(
                    a[mi], bb[1], accR[mi], 0, 0, 0);
#pragma unroll
            for (int mi = 0; mi < 4; ++mi)
                accC[mi] = __builtin_amdgcn_mfma_f32_16x16x32_bf16(
                    a[mi], bb[2], accC[mi], 0, 0, 0);
            __builtin_amdgcn_s_setprio(0);
        }
    };

    // unrolled x2: buf is compile-time 0/1
    for (int kp = 0; kp < 4; ++kp) {
        body(kp * 2, 0, accCx);
        body(kp * 2 + 1, 1, accCx);
    }
    for (int kp = 4; kp < 8; ++kp) {
        body(kp * 2, 0, accCh);
        body(kp * 2 + 1, 1, accCh);
    }

    // ---- fused epilogue ----
    {
        const int col = nb * 64 + wn * 16 + cl;
        const float bU = bu[col];
        const float bR = br[col];
        const float bC = bc[col];
#pragma unroll
        for (int mi = 0; mi < 4; ++mi) {
#pragma unroll
            for (int j = 0; j < 4; ++j) {
                const int row = mb * 128 + wm * 64 + mi * 16 + kg * 4 + j;
                const float up = accU[mi][j] + bU;
                const float rp = accR[mi][j] + bR;
                const float u = 1.f / (1.f + __expf(-up));
                const float r = 1.f / (1.f + __expf(-rp));
                const float cpre = accCx[mi][j] + bC + r * accCh[mi][j];
                const float e = __expf(-2.f * cpre);
                const float cc = (1.f - e) / (1.f + e);   // tanh
                const float aa = att[row];
                const float hv = h[(size_t)row * 512 + col];
                const float u_ = aa * u;
                out[(size_t)row * 512 + col] = (1.f - u_) * hv + u_ * cc;
            }
        }
    }
}

extern "C" void kernel_launch(void* const* d_in, const int* in_sizes, int n_in,
                              void* d_out, int out_size, void* d_ws, size_t ws_size,
                              hipStream_t stream) {
    const float* x    = (const float*)d_in[0];
    const float* h    = (const float*)d_in[1];
    const float* att  = (const float*)d_in[2];
    const float* Wu_x = (const float*)d_in[3];
    const float* bu   = (const float*)d_in[4];
    const float* Wu_h = (const float*)d_in[5];
    const float* Wr_x = (const float*)d_in[6];
    const float* br   = (const float*)d_in[7];
    const float* Wr_h = (const float*)d_in[8];
    const float* Wc_x = (const float*)d_in[9];
    const float* bc   = (const float*)d_in[10];
    const float* Wc_h = (const float*)d_in[11];
    unsigned short* Wt2 = (unsigned short*)d_ws;                        // 3 MB @ 0
    unsigned short* Apack = (unsigned short*)((char*)d_ws + (4 << 20)); // 64 MB @ 4MB
    float* out = (float*)d_out;

    prep_weights<<<dim3(32, 16, 3), 256, 0, stream>>>(Wu_x, Wu_h, Wr_x, Wr_h, Wc_x, Wc_h, Wt2);
    prep_A<<<dim3(8192), 512, 0, stream>>>(x, h, Apack);

    hipFuncSetAttribute((const void*)augru_main,
                        hipFuncAttributeMaxDynamicSharedMemorySize, 2 * BUF);
    augru_main<<<dim3(2048), THREADS, 2 * BUF, stream>>>(
        h, att, Wt2, Apack, bu, br, bc, out);
}

// Round 8
// 152.552 us; speedup vs baseline: 1.8199x; 1.8199x over previous
//
#include <hip/hip_runtime.h>
#include <hip/hip_bf16.h>
#include <stdint.h>

#define B_ROWS 32768
#define DIM 512
#define THREADS 512
#define NKT 32              // K-steps of 32 over K=1024
#define ABUF 8192           // 128 rows x 64 B
#define WBUF 24576          // 3 mats x 128 cols x 64 B
#define BUF (ABUF + WBUF)   // 32 KB per stage; x4 buffers = 128 KB, 1 block/CU

typedef __attribute__((ext_vector_type(8))) __bf16 bf16x8;
typedef __attribute__((ext_vector_type(4))) float f32x4;
typedef __attribute__((ext_vector_type(4))) unsigned int uint4v;

__device__ static inline unsigned short f2bf(float f) {
    unsigned int u = __builtin_bit_cast(unsigned int, f);
    u += 0x7fffu + ((u >> 16) & 1u);
    return (unsigned short)(u >> 16);
}

__device__ static inline void load_lds_16B(const void* g, void* lds) {
    __builtin_amdgcn_global_load_lds(
        (const __attribute__((address_space(1))) unsigned int*)g,
        (__attribute__((address_space(3))) unsigned int*)lds,
        16, 0, 0);
}

// Wt2[kt 0..31][t 0..2][n 0..511][64B]: element (t,n,k): kt=k>>5, kc=k&31,
// byte = (kc*2) ^ (((n>>1)&3)<<4).   (identical to round-5/6 layout, 0-conflict)
__global__ void prep_weights(const float* __restrict__ Wu_x, const float* __restrict__ Wu_h,
                             const float* __restrict__ Wr_x, const float* __restrict__ Wr_h,
                             const float* __restrict__ Wc_x, const float* __restrict__ Wc_h,
                             unsigned short* __restrict__ Wt2) {
    __shared__ float tile[32][33];
    const int t = blockIdx.z;
    const int k0 = blockIdx.x * 32;
    const int n0 = blockIdx.y * 32;
    const float* Wx = (t == 0) ? Wu_x : (t == 1) ? Wr_x : Wc_x;
    const float* Wh = (t == 0) ? Wu_h : (t == 1) ? Wr_h : Wc_h;
    const int tid = threadIdx.x;
    const int c = tid & 31, r0 = tid >> 5;
#pragma unroll
    for (int i = 0; i < 4; ++i) {
        int kl = r0 + i * 8;
        int k = k0 + kl;
        int n = n0 + c;
        float v = (k < 512) ? Wx[(size_t)k * 512 + n] : Wh[(size_t)(k - 512) * 512 + n];
        tile[kl][c] = v;
    }
    __syncthreads();
    const int kt = k0 >> 5;
#pragma unroll
    for (int i = 0; i < 4; ++i) {
        int nl = r0 + i * 8;
        int kc = c;
        int n = n0 + nl;
        size_t base = (((size_t)kt * 3 + t) * 512 + n) * 64;
        *(unsigned short*)((char*)Wt2 + base + ((kc * 2) ^ (((n >> 1) & 3) << 4))) =
            f2bf(tile[kc][nl]);
    }
}

// Apack[kt 0..31][row 0..32767][64B]: 16B slot s of row r at byte
// (s*16) ^ (((r>>1)&3)<<4). kt<16 from x, else from h. (round-5/6 layout)
__global__ __launch_bounds__(512) void prep_A(const float* __restrict__ x,
                                              const float* __restrict__ h,
                                              unsigned short* __restrict__ Apack) {
    const size_t i = (size_t)blockIdx.x * 512 + threadIdx.x;  // 16B chunk id
    const int slot = (int)(i & 3);
    const int row = (int)((i >> 2) & 32767);
    const int kt = (int)(i >> 17);
    const int k0 = kt * 32 + slot * 8;   // 0..1023
    const float* src = (k0 < 512) ? (x + (size_t)row * 512 + k0)
                                  : (h + (size_t)row * 512 + (k0 - 512));
    float4 f0 = *(const float4*)(src + 0);
    float4 f1 = *(const float4*)(src + 4);
    uint4v p;
    p.x = f2bf(f0.x) | ((unsigned)f2bf(f0.y) << 16);
    p.y = f2bf(f0.z) | ((unsigned)f2bf(f0.w) << 16);
    p.z = f2bf(f1.x) | ((unsigned)f2bf(f1.y) << 16);
    p.w = f2bf(f1.z) | ((unsigned)f2bf(f1.w) << 16);
    char* dst = (char*)Apack + (((size_t)kt << 15) + row) * 64
              + ((slot * 16) ^ (((row >> 1) & 3) << 4));
    *(uint4v*)dst = p;
}

// -- main: BM=128 BN=128 BK=32, wave tile 64x32, 4x32KB buffers, counted vmcnt --
__global__ __launch_bounds__(THREADS, 2) void augru_main(
    const float* __restrict__ h, const float* __restrict__ att,
    const unsigned short* __restrict__ Wt2, const unsigned short* __restrict__ Apack,
    const float* __restrict__ bu, const float* __restrict__ br,
    const float* __restrict__ bc, float* __restrict__ out) {
    extern __shared__ char smem[];   // 4 x 32 KB
    const int tid = threadIdx.x;
    const int lane = tid & 63;
    const int wid = tid >> 6;
    const int wm = wid >> 2;   // 0..1 -> 64-row half
    const int wn = wid & 3;    // 0..3 -> 32-col slice
    const int id = blockIdx.x;
    const int wg = (id & 7) * 128 + (id >> 3);   // XCD-bijective (1024%8==0)
    const int nb = wg & 3;     // 0..3 -> 128-col block
    const int mb = wg >> 2;    // 0..255
    const int cl = lane & 15;
    const int kg = lane >> 4;

    f32x4 accU[4][2], accR[4][2], accCx[4][2], accCh[4][2];
#pragma unroll
    for (int i = 0; i < 4; ++i)
#pragma unroll
        for (int j = 0; j < 2; ++j) {
            accU[i][j] = (f32x4)(0.f);
            accR[i][j] = (f32x4)(0.f);
            accCx[i][j] = (f32x4)(0.f);
            accCh[i][j] = (f32x4)(0.f);
        }

    // hoisted ds_read byte offsets (10 ints)
    int aOff[4], wOff[3][2];
#pragma unroll
    for (int mi = 0; mi < 4; ++mi) {
        const int row = wm * 64 + mi * 16 + cl;
        aOff[mi] = row * 64 + ((kg * 16) ^ (((row >> 1) & 3) << 4));
    }
#pragma unroll
    for (int t = 0; t < 3; ++t)
#pragma unroll
        for (int ni = 0; ni < 2; ++ni) {
            const int col = wn * 32 + ni * 16 + cl;
            wOff[t][ni] = ABUF + t * 8192 + col * 64
                        + ((kg * 16) ^ (((col >> 1) & 3) << 4));
        }

    // staging bases (per-thread); per stage add kt * stride
    const char* gA0 = (const char*)Apack + ((size_t)mb * 128) * 64 + tid * 16;
    const char* gW0 = (const char*)Wt2 + ((size_t)nb * 128) * 64 + tid * 16;

    auto stage = [&](int buf, int kt) {
        char* base = smem + buf * BUF;
        const size_t kA = (size_t)kt * (32768 * 64);
        const size_t kW = (size_t)kt * (3 * 512 * 64);
        load_lds_16B(gA0 + kA, base + wid * 1024);                       // A 8 KB
#pragma unroll
        for (int t = 0; t < 3; ++t)                                      // W 24 KB
            load_lds_16B(gW0 + kW + t * (512 * 64),
                         base + ABUF + t * 8192 + wid * 1024);
    };

    stage(0, 0);
    stage(1, 1);
    stage(2, 2);

    auto body = [&](int kt, int buf, int wait, f32x4(&accC)[4][2]) {
        if (wait == 8)      asm volatile("s_waitcnt vmcnt(8)" ::: "memory");
        else if (wait == 4) asm volatile("s_waitcnt vmcnt(4)" ::: "memory");
        else                asm volatile("s_waitcnt vmcnt(0)" ::: "memory");
        __builtin_amdgcn_s_barrier();        // stage(kt) landed; buf(kt-1) reads done
        if (kt + 3 < NKT) stage((kt + 3) & 3, kt + 3);   // ~3 iters of flight
        const char* aB = smem + buf * BUF;
        bf16x8 a[4], bb[3][2];
#pragma unroll
        for (int mi = 0; mi < 4; ++mi)
            a[mi] = __builtin_bit_cast(bf16x8, *(const uint4v*)(aB + aOff[mi]));
#pragma unroll
        for (int t = 0; t < 3; ++t)
#pragma unroll
            for (int ni = 0; ni < 2; ++ni)
                bb[t][ni] = __builtin_bit_cast(bf16x8,
                    *(const uint4v*)(aB + wOff[t][ni]));
        __builtin_amdgcn_s_setprio(1);
#pragma unroll
        for (int ni = 0; ni < 2; ++ni) {
#pragma unroll
            for (int mi = 0; mi < 4; ++mi)
                accU[mi][ni] = __builtin_amdgcn_mfma_f32_16x16x32_bf16(
                    a[mi], bb[0][ni], accU[mi][ni], 0, 0, 0);
#pragma unroll
            for (int mi = 0; mi < 4; ++mi)
                accR[mi][ni] = __builtin_amdgcn_mfma_f32_16x16x32_bf16(
                    a[mi], bb[1][ni], accR[mi][ni], 0, 0, 0);
#pragma unroll
            for (int mi = 0; mi < 4; ++mi)
                accC[mi][ni] = __builtin_amdgcn_mfma_f32_16x16x32_bf16(
                    a[mi], bb[2][ni], accC[mi][ni], 0, 0, 0);
        }
        __builtin_amdgcn_s_setprio(0);
    };

    for (int g = 0; g < 4; ++g) {          // x-half -> cx (kt 0..15)
        const int k0 = g * 4;
        body(k0 + 0, 0, 8, accCx);
        body(k0 + 1, 1, 8, accCx);
        body(k0 + 2, 2, 8, accCx);
        body(k0 + 3, 3, 8, accCx);
    }
    for (int g = 4; g < 7; ++g) {          // h-half -> ch (kt 16..27)
        const int k0 = g * 4;
        body(k0 + 0, 0, 8, accCh);
        body(k0 + 1, 1, 8, accCh);
        body(k0 + 2, 2, 8, accCh);
        body(k0 + 3, 3, 8, accCh);
    }
    body(28, 0, 8, accCh);                 // tail with draining waits
    body(29, 1, 8, accCh);
    body(30, 2, 4, accCh);
    body(31, 3, 0, accCh);

    // ---- fused epilogue ----
#pragma unroll
    for (int ni = 0; ni < 2; ++ni) {
        const int col = nb * 128 + wn * 32 + ni * 16 + cl;
        const float bU = bu[col];
        const float bR = br[col];
        const float bC = bc[col];
#pragma unroll
        for (int mi = 0; mi < 4; ++mi) {
#pragma unroll
            for (int j = 0; j < 4; ++j) {
                const int row = mb * 128 + wm * 64 + mi * 16 + kg * 4 + j;
                const float up = accU[mi][ni][j] + bU;
                const float rp = accR[mi][ni][j] + bR;
                const float u = 1.f / (1.f + __expf(-up));
                const float r = 1.f / (1.f + __expf(-rp));
                const float cpre = accCx[mi][ni][j] + bC + r * accCh[mi][ni][j];
                const float e = __expf(-2.f * cpre);
                const float cc = (1.f - e) / (1.f + e);   // tanh
                const float aa = att[row];
                const float hv = h[(size_t)row * 512 + col];
                const float u_ = aa * u;
                out[(size_t)row * 512 + col] = (1.f - u_) * hv + u_ * cc;
            }
        }
    }
}

extern "C" void kernel_launch(void* const* d_in, const int* in_sizes, int n_in,
                              void* d_out, int out_size, void* d_ws, size_t ws_size,
                              hipStream_t stream) {
    const float* x    = (const float*)d_in[0];
    const float* h    = (const float*)d_in[1];
    const float* att  = (const float*)d_in[2];
    const float* Wu_x = (const float*)d_in[3];
    const float* bu   = (const float*)d_in[4];
    const float* Wu_h = (const float*)d_in[5];
    const float* Wr_x = (const float*)d_in[6];
    const float* br   = (const float*)d_in[7];
    const float* Wr_h = (const float*)d_in[8];
    const float* Wc_x = (const float*)d_in[9];
    const float* bc   = (const float*)d_in[10];
    const float* Wc_h = (const float*)d_in[11];
    unsigned short* Wt2 = (unsigned short*)d_ws;                        // 3 MB @ 0
    unsigned short* Apack = (unsigned short*)((char*)d_ws + (4 << 20)); // 64 MB @ 4MB
    float* out = (float*)d_out;

    prep_weights<<<dim3(32, 16, 3), 256, 0, stream>>>(Wu_x, Wu_h, Wr_x, Wr_h, Wc_x, Wc_h, Wt2);
    prep_A<<<dim3(8192), 512, 0, stream>>>(x, h, Apack);

    hipFuncSetAttribute((const void*)augru_main,
                        hipFuncAttributeMaxDynamicSharedMemorySize, 4 * BUF);
    augru_main<<<dim3(1024), THREADS, 4 * BUF, stream>>>(
        h, att, Wt2, Apack, bu, br, bc, out);
}

// Round 9
// 148.306 us; speedup vs baseline: 1.8720x; 1.0286x over previous
//
#include <hip/hip_runtime.h>
#include <hip/hip_bf16.h>
#include <stdint.h>

#define B_ROWS 32768
#define DIM 512
#define THREADS 256
#define NKT 16              // K-steps of 64 over K=1024
#define ABUF 16384          // 128 rows x 128 B
#define WBUF 24576          // 3 mats x 64 cols x 128 B
#define BUF (ABUF + WBUF)   // 40 KB per stage; x2 = 80 KB/block; 2 blocks = 160 KiB

typedef __attribute__((ext_vector_type(8))) __bf16 bf16x8;
typedef __attribute__((ext_vector_type(4))) float f32x4;
typedef __attribute__((ext_vector_type(4))) unsigned int uint4v;

__device__ static inline unsigned short f2bf(float f) {
    unsigned int u = __builtin_bit_cast(unsigned int, f);
    u += 0x7fffu + ((u >> 16) & 1u);
    return (unsigned short)(u >> 16);
}

__device__ static inline void load_lds_16B(const void* g, void* lds) {
    __builtin_amdgcn_global_load_lds(
        (const __attribute__((address_space(1))) unsigned int*)g,
        (__attribute__((address_space(3))) unsigned int*)lds,
        16, 0, 0);
}

// Wt2[kt 0..15][t 0..2][n 0..511][128B]: byte = (kk*2) ^ ((n&7)<<4), kk=k&63.
// (validated in round 7)
__global__ void prep_weights(const float* __restrict__ Wu_x, const float* __restrict__ Wu_h,
                             const float* __restrict__ Wr_x, const float* __restrict__ Wr_h,
                             const float* __restrict__ Wc_x, const float* __restrict__ Wc_h,
                             unsigned short* __restrict__ Wt2) {
    __shared__ float tile[32][33];
    const int t = blockIdx.z;
    const int k0 = blockIdx.x * 32;
    const int n0 = blockIdx.y * 32;
    const float* Wx = (t == 0) ? Wu_x : (t == 1) ? Wr_x : Wc_x;
    const float* Wh = (t == 0) ? Wu_h : (t == 1) ? Wr_h : Wc_h;
    const int tid = threadIdx.x;
    const int c = tid & 31, r0 = tid >> 5;
#pragma unroll
    for (int i = 0; i < 4; ++i) {
        int kl = r0 + i * 8;
        int k = k0 + kl;
        int n = n0 + c;
        float v = (k < 512) ? Wx[(size_t)k * 512 + n] : Wh[(size_t)(k - 512) * 512 + n];
        tile[kl][c] = v;
    }
    __syncthreads();
    const int kt = k0 >> 6;
    const int kkb = k0 & 32;
#pragma unroll
    for (int i = 0; i < 4; ++i) {
        int nl = r0 + i * 8;
        int kc = c;
        int n = n0 + nl;
        size_t base = (((size_t)kt * 3 + t) * 512 + n) * 128;
        *(unsigned short*)((char*)Wt2 + base + (((kkb + kc) * 2) ^ ((n & 7) << 4))) =
            f2bf(tile[kc][nl]);
    }
}

// Apack[kt 0..15][row 0..32767][128B]: slot s (0..7) at (s*16) ^ ((row&7)<<4).
// (validated in round 7)
__global__ __launch_bounds__(512) void prep_A(const float* __restrict__ x,
                                              const float* __restrict__ h,
                                              unsigned short* __restrict__ Apack) {
    const size_t i = (size_t)blockIdx.x * 512 + threadIdx.x;  // 16B chunk id (4M)
    const int s = (int)(i & 7);
    const int row = (int)((i >> 3) & 32767);
    const int kt = (int)(i >> 18);
    const int k0 = kt * 64 + s * 8;   // 0..1016
    const float* src = (k0 < 512) ? (x + (size_t)row * 512 + k0)
                                  : (h + (size_t)row * 512 + (k0 - 512));
    float4 f0 = *(const float4*)(src + 0);
    float4 f1 = *(const float4*)(src + 4);
    uint4v p;
    p.x = f2bf(f0.x) | ((unsigned)f2bf(f0.y) << 16);
    p.y = f2bf(f0.z) | ((unsigned)f2bf(f0.w) << 16);
    p.z = f2bf(f1.x) | ((unsigned)f2bf(f1.y) << 16);
    p.w = f2bf(f1.z) | ((unsigned)f2bf(f1.w) << 16);
    char* dst = (char*)Apack + (((size_t)kt * 32768 + row) * 128)
              + ((s * 16) ^ ((row & 7) << 4));
    *(uint4v*)dst = p;
}

// -- main: 256-thr blocks (wave 64x32, block 128x64), BK=64, 2x40KB, 2 blocks/CU
__global__ __launch_bounds__(THREADS, 2) void augru_main(
    const float* __restrict__ h, const float* __restrict__ att,
    const unsigned short* __restrict__ Wt2, const unsigned short* __restrict__ Apack,
    const float* __restrict__ bu, const float* __restrict__ br,
    const float* __restrict__ bc, float* __restrict__ out) {
    extern __shared__ char smem[];   // 2 x 40 KB
    const int tid = threadIdx.x;
    const int lane = tid & 63;
    const int wid = tid >> 6;   // 0..3
    const int wm = wid >> 1;    // 0..1 -> 64-row half
    const int wn = wid & 1;     // 0..1 -> 32-col half
    const int id = blockIdx.x;
    const int wg = (id & 7) * 256 + (id >> 3);   // XCD-bijective (2048%8==0)
    const int nb = wg & 7;      // 0..7 -> 64-col block
    const int mb = wg >> 3;     // 0..255
    const int cl = lane & 15;
    const int kg = lane >> 4;

    f32x4 accU[4][2], accR[4][2], accCx[4][2], accCh[4][2];
#pragma unroll
    for (int i = 0; i < 4; ++i)
#pragma unroll
        for (int j = 0; j < 2; ++j) {
            accU[i][j] = (f32x4)(0.f);
            accR[i][j] = (f32x4)(0.f);
            accCx[i][j] = (f32x4)(0.f);
            accCh[i][j] = (f32x4)(0.f);
        }

    // hoisted ds_read byte offsets
    int aOff[2][4], wOff[2][3][2];
#pragma unroll
    for (int ks = 0; ks < 2; ++ks) {
        const int kbyte = ks * 64 + kg * 16;
#pragma unroll
        for (int mi = 0; mi < 4; ++mi) {
            const int row = wm * 64 + mi * 16 + cl;
            aOff[ks][mi] = row * 128 + (kbyte ^ ((row & 7) << 4));
        }
#pragma unroll
        for (int t = 0; t < 3; ++t)
#pragma unroll
            for (int ni = 0; ni < 2; ++ni) {
                const int col = wn * 32 + ni * 16 + cl;
                wOff[ks][t][ni] = ABUF + t * 8192 + col * 128
                                + (kbyte ^ ((col & 7) << 4));
            }
    }

    // staging bases
    const char* gA0 = (const char*)Apack + (size_t)mb * 128 * 128;  // + kt*32768*128
    const char* gW0 = (const char*)Wt2 + (size_t)nb * 64 * 128;     // + kt*3*512*128

    auto stage = [&](int buf, int kt) {
        char* base = smem + buf * BUF;
        const char* gA = gA0 + (size_t)kt * (32768 * 128);
        const char* gW = gW0 + (size_t)kt * (3 * 512 * 128);
#pragma unroll
        for (int q = 0; q < 4; ++q) {   // A: 16 KB
            const int b = q * 4096 + tid * 16;
            load_lds_16B(gA + b, base + q * 4096 + wid * 1024);
        }
#pragma unroll
        for (int q = 0; q < 6; ++q) {   // W: 24 KB; t = q>>1 (wave-uniform, 4KB spans)
            const int t = q >> 1;
            const int b = (q & 1) * 4096 + tid * 16;
            load_lds_16B(gW + (size_t)t * (512 * 128) + b,
                         base + ABUF + q * 4096 + wid * 1024);
        }
    };

    stage(0, 0);

    auto body = [&](int kt, int buf, f32x4(&accC)[4][2]) {
        asm volatile("s_waitcnt vmcnt(0)" ::: "memory");  // stage(kt) landed
        __builtin_amdgcn_s_barrier();                     // buf^1 reads all done
        if (kt + 1 < NKT) stage(buf ^ 1, kt + 1);         // full iter of flight
        const char* aB = smem + buf * BUF;
#pragma unroll
        for (int ks = 0; ks < 2; ++ks) {
            bf16x8 a[4], bb[3][2];
#pragma unroll
            for (int mi = 0; mi < 4; ++mi)
                a[mi] = __builtin_bit_cast(bf16x8, *(const uint4v*)(aB + aOff[ks][mi]));
#pragma unroll
            for (int t = 0; t < 3; ++t)
#pragma unroll
                for (int ni = 0; ni < 2; ++ni)
                    bb[t][ni] = __builtin_bit_cast(bf16x8,
                        *(const uint4v*)(aB + wOff[ks][t][ni]));
            __builtin_amdgcn_s_setprio(1);
#pragma unroll
            for (int ni = 0; ni < 2; ++ni) {
#pragma unroll
                for (int mi = 0; mi < 4; ++mi)
                    accU[mi][ni] = __builtin_amdgcn_mfma_f32_16x16x32_bf16(
                        a[mi], bb[0][ni], accU[mi][ni], 0, 0, 0);
#pragma unroll
                for (int mi = 0; mi < 4; ++mi)
                    accR[mi][ni] = __builtin_amdgcn_mfma_f32_16x16x32_bf16(
                        a[mi], bb[1][ni], accR[mi][ni], 0, 0, 0);
#pragma unroll
                for (int mi = 0; mi < 4; ++mi)
                    accC[mi][ni] = __builtin_amdgcn_mfma_f32_16x16x32_bf16(
                        a[mi], bb[2][ni], accC[mi][ni], 0, 0, 0);
            }
            __builtin_amdgcn_s_setprio(0);
        }
    };

    for (int g = 0; g < 4; ++g) {           // kt 0..7: x-half -> cx
        body(g * 2, 0, accCx);
        body(g * 2 + 1, 1, accCx);
    }
    for (int g = 4; g < 8; ++g) {           // kt 8..15: h-half -> ch
        body(g * 2, 0, accCh);
        body(g * 2 + 1, 1, accCh);
    }

    // ---- fused epilogue ----
#pragma unroll
    for (int ni = 0; ni < 2; ++ni) {
        const int col = nb * 64 + wn * 32 + ni * 16 + cl;
        const float bU = bu[col];
        const float bR = br[col];
        const float bC = bc[col];
#pragma unroll
        for (int mi = 0; mi < 4; ++mi) {
#pragma unroll
            for (int j = 0; j < 4; ++j) {
                const int row = mb * 128 + wm * 64 + mi * 16 + kg * 4 + j;
                const float up = accU[mi][ni][j] + bU;
                const float rp = accR[mi][ni][j] + bR;
                const float u = 1.f / (1.f + __expf(-up));
                const float r = 1.f / (1.f + __expf(-rp));
                const float cpre = accCx[mi][ni][j] + bC + r * accCh[mi][ni][j];
                const float e = __expf(-2.f * cpre);
                const float cc = (1.f - e) / (1.f + e);   // tanh
                const float aa = att[row];
                const float hv = h[(size_t)row * 512 + col];
                const float u_ = aa * u;
                out[(size_t)row * 512 + col] = (1.f - u_) * hv + u_ * cc;
            }
        }
    }
}

extern "C" void kernel_launch(void* const* d_in, const int* in_sizes, int n_in,
                              void* d_out, int out_size, void* d_ws, size_t ws_size,
                              hipStream_t stream) {
    const float* x    = (const float*)d_in[0];
    const float* h    = (const float*)d_in[1];
    const float* att  = (const float*)d_in[2];
    const float* Wu_x = (const float*)d_in[3];
    const float* bu   = (const float*)d_in[4];
    const float* Wu_h = (const float*)d_in[5];
    const float* Wr_x = (const float*)d_in[6];
    const float* br   = (const float*)d_in[7];
    const float* Wr_h = (const float*)d_in[8];
    const float* Wc_x = (const float*)d_in[9];
    const float* bc   = (const float*)d_in[10];
    const float* Wc_h = (const float*)d_in[11];
    unsigned short* Wt2 = (unsigned short*)d_ws;                        // 3 MB @ 0
    unsigned short* Apack = (unsigned short*)((char*)d_ws + (4 << 20)); // 64 MB @ 4MB
    float* out = (float*)d_out;

    prep_weights<<<dim3(32, 16, 3), 256, 0, stream>>>(Wu_x, Wu_h, Wr_x, Wr_h, Wc_x, Wc_h, Wt2);
    prep_A<<<dim3(8192), 512, 0, stream>>>(x, h, Apack);

    hipFuncSetAttribute((const void*)augru_main,
                        hipFuncAttributeMaxDynamicSharedMemorySize, 2 * BUF);
    augru_main<<<dim3(2048), THREADS, 2 * BUF, stream>>>(
        h, att, Wt2, Apack, bu, br, bc, out);
}

// Round 10
// 147.322 us; speedup vs baseline: 1.8845x; 1.0067x over previous
//
#include <hip/hip_runtime.h>
#include <hip/hip_bf16.h>
#include <stdint.h>

#define B_ROWS 32768
#define DIM 512
#define THREADS 256
#define NKT 32              // K-steps of 32 over K=1024
#define ABUF 8192           // 128 rows x 64 B
#define WBUF 12288          // 3 mats x 64 cols x 64 B
#define BUF (ABUF + WBUF)   // 20 KB per stage; x4 = 80 KB/block; 2 blocks = 160 KiB

typedef __attribute__((ext_vector_type(8))) __bf16 bf16x8;
typedef __attribute__((ext_vector_type(4))) float f32x4;
typedef __attribute__((ext_vector_type(4))) unsigned int uint4v;

__device__ static inline unsigned short f2bf(float f) {
    unsigned int u = __builtin_bit_cast(unsigned int, f);
    u += 0x7fffu + ((u >> 16) & 1u);
    return (unsigned short)(u >> 16);
}

__device__ static inline void load_lds_16B(const void* g, void* lds) {
    __builtin_amdgcn_global_load_lds(
        (const __attribute__((address_space(1))) unsigned int*)g,
        (__attribute__((address_space(3))) unsigned int*)lds,
        16, 0, 0);
}

// Wt2[kt 0..31][t 0..2][n 0..511][64B]: element (t,n,k): kt=k>>5, kc=k&31,
// byte = (kc*2) ^ (((n>>1)&3)<<4).   (round-5/6 layout, validated, 0-conflict)
__global__ void prep_weights(const float* __restrict__ Wu_x, const float* __restrict__ Wu_h,
                             const float* __restrict__ Wr_x, const float* __restrict__ Wr_h,
                             const float* __restrict__ Wc_x, const float* __restrict__ Wc_h,
                             unsigned short* __restrict__ Wt2) {
    __shared__ float tile[32][33];
    const int t = blockIdx.z;
    const int k0 = blockIdx.x * 32;
    const int n0 = blockIdx.y * 32;
    const float* Wx = (t == 0) ? Wu_x : (t == 1) ? Wr_x : Wc_x;
    const float* Wh = (t == 0) ? Wu_h : (t == 1) ? Wr_h : Wc_h;
    const int tid = threadIdx.x;
    const int c = tid & 31, r0 = tid >> 5;
#pragma unroll
    for (int i = 0; i < 4; ++i) {
        int kl = r0 + i * 8;
        int k = k0 + kl;
        int n = n0 + c;
        float v = (k < 512) ? Wx[(size_t)k * 512 + n] : Wh[(size_t)(k - 512) * 512 + n];
        tile[kl][c] = v;
    }
    __syncthreads();
    const int kt = k0 >> 5;
#pragma unroll
    for (int i = 0; i < 4; ++i) {
        int nl = r0 + i * 8;
        int kc = c;
        int n = n0 + nl;
        size_t base = (((size_t)kt * 3 + t) * 512 + n) * 64;
        *(unsigned short*)((char*)Wt2 + base + ((kc * 2) ^ (((n >> 1) & 3) << 4))) =
            f2bf(tile[kc][nl]);
    }
}

// Apack[kt 0..31][row 0..32767][64B]: 16B slot s of row r at byte
// (s*16) ^ (((r>>1)&3)<<4). kt<16 from x, else from h. (round-5/6 layout)
__global__ __launch_bounds__(512) void prep_A(const float* __restrict__ x,
                                              const float* __restrict__ h,
                                              unsigned short* __restrict__ Apack) {
    const size_t i = (size_t)blockIdx.x * 512 + threadIdx.x;  // 16B chunk id
    const int slot = (int)(i & 3);
    const int row = (int)((i >> 2) & 32767);
    const int kt = (int)(i >> 17);
    const int k0 = kt * 32 + slot * 8;   // 0..1023
    const float* src = (k0 < 512) ? (x + (size_t)row * 512 + k0)
                                  : (h + (size_t)row * 512 + (k0 - 512));
    float4 f0 = *(const float4*)(src + 0);
    float4 f1 = *(const float4*)(src + 4);
    uint4v p;
    p.x = f2bf(f0.x) | ((unsigned)f2bf(f0.y) << 16);
    p.y = f2bf(f0.z) | ((unsigned)f2bf(f0.w) << 16);
    p.z = f2bf(f1.x) | ((unsigned)f2bf(f1.y) << 16);
    p.w = f2bf(f1.z) | ((unsigned)f2bf(f1.w) << 16);
    char* dst = (char*)Apack + (((size_t)kt << 15) + row) * 64
              + ((slot * 16) ^ (((row >> 1) & 3) << 4));
    *(uint4v*)dst = p;
}

// main: 256-thr, wave 64x32, block 128x64, BK=32, 4x20KB buffers, depth-3 vmcnt
__global__ __launch_bounds__(THREADS, 2) void augru_main(
    const float* __restrict__ h, const float* __restrict__ att,
    const unsigned short* __restrict__ Wt2, const unsigned short* __restrict__ Apack,
    const float* __restrict__ bu, const float* __restrict__ br,
    const float* __restrict__ bc, float* __restrict__ out) {
    extern __shared__ char smem[];   // 4 x 20 KB
    const int tid = threadIdx.x;
    const int lane = tid & 63;
    const int wid = tid >> 6;   // 0..3
    const int wm = wid >> 1;    // 0..1 -> 64-row half
    const int wn = wid & 1;     // 0..1 -> 32-col half
    const int id = blockIdx.x;
    const int wg = (id & 7) * 256 + (id >> 3);   // XCD-bijective (2048%8==0)
    const int nb = wg & 7;      // 0..7 -> 64-col block
    const int mb = wg >> 3;     // 0..255
    const int cl = lane & 15;
    const int kg = lane >> 4;

    f32x4 accU[4][2], accR[4][2], accCx[4][2], accCh[4][2];
#pragma unroll
    for (int i = 0; i < 4; ++i)
#pragma unroll
        for (int j = 0; j < 2; ++j) {
            accU[i][j] = (f32x4)(0.f);
            accR[i][j] = (f32x4)(0.f);
            accCx[i][j] = (f32x4)(0.f);
            accCh[i][j] = (f32x4)(0.f);
        }

    // hoisted ds_read byte offsets (10 ints)
    int aOff[4], wOff[3][2];
#pragma unroll
    for (int mi = 0; mi < 4; ++mi) {
        const int row = wm * 64 + mi * 16 + cl;
        aOff[mi] = row * 64 + ((kg * 16) ^ (((row >> 1) & 3) << 4));
    }
#pragma unroll
    for (int t = 0; t < 3; ++t)
#pragma unroll
        for (int ni = 0; ni < 2; ++ni) {
            const int col = wn * 32 + ni * 16 + cl;
            wOff[t][ni] = ABUF + t * 4096 + col * 64
                        + ((kg * 16) ^ (((col >> 1) & 3) << 4));
        }

    // staging bases; 5 loads/thread/stage (2 A + 3 W), uniform across waves
    const char* gA0 = (const char*)Apack + ((size_t)mb * 128) * 64 + tid * 16;
    const char* gW0 = (const char*)Wt2 + ((size_t)nb * 64) * 64 + tid * 16;

    auto stage = [&](int buf, int kt) {
        char* base = smem + buf * BUF;
        const char* gA = gA0 + (size_t)kt * (32768 * 64);
        const char* gW = gW0 + (size_t)kt * (3 * 512 * 64);
        load_lds_16B(gA, base + wid * 1024);
        load_lds_16B(gA + 4096, base + 4096 + wid * 1024);
#pragma unroll
        for (int t = 0; t < 3; ++t)
            load_lds_16B(gW + (size_t)t * (512 * 64),
                         base + ABUF + t * 4096 + wid * 1024);
    };

    stage(0, 0);
    stage(1, 1);
    stage(2, 2);

    auto body = [&](int kt, int buf, int wait, f32x4(&accC)[4][2]) {
        if (wait == 10)     asm volatile("s_waitcnt vmcnt(10)" ::: "memory");
        else if (wait == 5) asm volatile("s_waitcnt vmcnt(5)" ::: "memory");
        else                asm volatile("s_waitcnt vmcnt(0)" ::: "memory");
        __builtin_amdgcn_s_barrier();        // stage(kt) landed; buf(kt-1) reads done
        if (kt + 3 < NKT) stage((kt + 3) & 3, kt + 3);   // ~3 iters of flight
        const char* aB = smem + buf * BUF;
        bf16x8 a[4], bb[3][2];
#pragma unroll
        for (int mi = 0; mi < 4; ++mi)
            a[mi] = __builtin_bit_cast(bf16x8, *(const uint4v*)(aB + aOff[mi]));
#pragma unroll
        for (int t = 0; t < 3; ++t)
#pragma unroll
            for (int ni = 0; ni < 2; ++ni)
                bb[t][ni] = __builtin_bit_cast(bf16x8,
                    *(const uint4v*)(aB + wOff[t][ni]));
        __builtin_amdgcn_s_setprio(1);
#pragma unroll
        for (int ni = 0; ni < 2; ++ni) {
#pragma unroll
            for (int mi = 0; mi < 4; ++mi)
                accU[mi][ni] = __builtin_amdgcn_mfma_f32_16x16x32_bf16(
                    a[mi], bb[0][ni], accU[mi][ni], 0, 0, 0);
#pragma unroll
            for (int mi = 0; mi < 4; ++mi)
                accR[mi][ni] = __builtin_amdgcn_mfma_f32_16x16x32_bf16(
                    a[mi], bb[1][ni], accR[mi][ni], 0, 0, 0);
#pragma unroll
            for (int mi = 0; mi < 4; ++mi)
                accC[mi][ni] = __builtin_amdgcn_mfma_f32_16x16x32_bf16(
                    a[mi], bb[2][ni], accC[mi][ni], 0, 0, 0);
        }
        __builtin_amdgcn_s_setprio(0);
    };

    for (int g = 0; g < 4; ++g) {           // kt 0..15: x-half -> cx
        const int k0 = g * 4;
        body(k0 + 0, 0, 10, accCx);
        body(k0 + 1, 1, 10, accCx);
        body(k0 + 2, 2, 10, accCx);
        body(k0 + 3, 3, 10, accCx);
    }
    for (int g = 4; g < 7; ++g) {           // kt 16..27: h-half -> ch
        const int k0 = g * 4;
        body(k0 + 0, 0, 10, accCh);
        body(k0 + 1, 1, 10, accCh);
        body(k0 + 2, 2, 10, accCh);
        body(k0 + 3, 3, 10, accCh);
    }
    body(28, 0, 10, accCh);                 // tail: draining waits
    body(29, 1, 10, accCh);
    body(30, 2, 5, accCh);
    body(31, 3, 0, accCh);

    // ---- fused epilogue ----
#pragma unroll
    for (int ni = 0; ni < 2; ++ni) {
        const int col = nb * 64 + wn * 32 + ni * 16 + cl;
        const float bU = bu[col];
        const float bR = br[col];
        const float bC = bc[col];
#pragma unroll
        for (int mi = 0; mi < 4; ++mi) {
#pragma unroll
            for (int j = 0; j < 4; ++j) {
                const int row = mb * 128 + wm * 64 + mi * 16 + kg * 4 + j;
                const float up = accU[mi][ni][j] + bU;
                const float rp = accR[mi][ni][j] + bR;
                const float u = 1.f / (1.f + __expf(-up));
                const float r = 1.f / (1.f + __expf(-rp));
                const float cpre = accCx[mi][ni][j] + bC + r * accCh[mi][ni][j];
                const float e = __expf(-2.f * cpre);
                const float cc = (1.f - e) / (1.f + e);   // tanh
                const float aa = att[row];
                const float hv = h[(size_t)row * 512 + col];
                const float u_ = aa * u;
                out[(size_t)row * 512 + col] = (1.f - u_) * hv + u_ * cc;
            }
        }
    }
}

extern "C" void kernel_launch(void* const* d_in, const int* in_sizes, int n_in,
                              void* d_out, int out_size, void* d_ws, size_t ws_size,
                              hipStream_t stream) {
    const float* x    = (const float*)d_in[0];
    const float* h    = (const float*)d_in[1];
    const float* att  = (const float*)d_in[2];
    const float* Wu_x = (const float*)d_in[3];
    const float* bu   = (const float*)d_in[4];
    const float* Wu_h = (const float*)d_in[5];
    const float* Wr_x = (const float*)d_in[6];
    const float* br   = (const float*)d_in[7];
    const float* Wr_h = (const float*)d_in[8];
    const float* Wc_x = (const float*)d_in[9];
    const float* bc   = (const float*)d_in[10];
    const float* Wc_h = (const float*)d_in[11];
    unsigned short* Wt2 = (unsigned short*)d_ws;                        // 3 MB @ 0
    unsigned short* Apack = (unsigned short*)((char*)d_ws + (4 << 20)); // 64 MB @ 4MB
    float* out = (float*)d_out;

    prep_weights<<<dim3(32, 16, 3), 256, 0, stream>>>(Wu_x, Wu_h, Wr_x, Wr_h, Wc_x, Wc_h, Wt2);
    prep_A<<<dim3(8192), 512, 0, stream>>>(x, h, Apack);

    hipFuncSetAttribute((const void*)augru_main,
                        hipFuncAttributeMaxDynamicSharedMemorySize, 4 * BUF);
    augru_main<<<dim3(2048), THREADS, 4 * BUF, stream>>>(
        h, att, Wt2, Apack, bu, br, bc, out);
}

// Round 11
// 139.004 us; speedup vs baseline: 1.9973x; 1.0598x over previous
//
#include <hip/hip_runtime.h>
#include <hip/hip_bf16.h>
#include <stdint.h>

#define B_ROWS 32768
#define DIM 512
#define THREADS 256
#define NKT 32              // K-steps of 32 over K=1024
#define ABUF 8192           // 128 rows x 64 B (bf16)
#define WBUF 12288          // 3 mats x 64 cols x 64 B
#define BUF (ABUF + WBUF)   // 20 KB per stage; x4 = 80 KB/block; 2 blocks = 160 KiB

typedef __attribute__((ext_vector_type(8))) __bf16 bf16x8;
typedef __attribute__((ext_vector_type(4))) float f32x4;
typedef __attribute__((ext_vector_type(4))) unsigned int uint4v;

__device__ static inline unsigned short f2bf(float f) {
    unsigned int u = __builtin_bit_cast(unsigned int, f);
    u += 0x7fffu + ((u >> 16) & 1u);
    return (unsigned short)(u >> 16);
}

__device__ static inline void load_lds_16B(const void* g, void* lds) {
    __builtin_amdgcn_global_load_lds(
        (const __attribute__((address_space(1))) unsigned int*)g,
        (__attribute__((address_space(3))) unsigned int*)lds,
        16, 0, 0);
}

// Wt2[kt 0..31][t 0..2][n 0..511][64B]: element (t,n,k): kt=k>>5, kc=k&31,
// byte = (kc*2) ^ (((n>>1)&3)<<4).   (validated layout, 0-conflict)
__global__ void prep_weights(const float* __restrict__ Wu_x, const float* __restrict__ Wu_h,
                             const float* __restrict__ Wr_x, const float* __restrict__ Wr_h,
                             const float* __restrict__ Wc_x, const float* __restrict__ Wc_h,
                             unsigned short* __restrict__ Wt2) {
    __shared__ float tile[32][33];
    const int t = blockIdx.z;
    const int k0 = blockIdx.x * 32;
    const int n0 = blockIdx.y * 32;
    const float* Wx = (t == 0) ? Wu_x : (t == 1) ? Wr_x : Wc_x;
    const float* Wh = (t == 0) ? Wu_h : (t == 1) ? Wr_h : Wc_h;
    const int tid = threadIdx.x;
    const int c = tid & 31, r0 = tid >> 5;
#pragma unroll
    for (int i = 0; i < 4; ++i) {
        int kl = r0 + i * 8;
        int k = k0 + kl;
        int n = n0 + c;
        float v = (k < 512) ? Wx[(size_t)k * 512 + n] : Wh[(size_t)(k - 512) * 512 + n];
        tile[kl][c] = v;
    }
    __syncthreads();
    const int kt = k0 >> 5;
#pragma unroll
    for (int i = 0; i < 4; ++i) {
        int nl = r0 + i * 8;
        int kc = c;
        int n = n0 + nl;
        size_t base = (((size_t)kt * 3 + t) * 512 + n) * 64;
        *(unsigned short*)((char*)Wt2 + base + ((kc * 2) ^ (((n >> 1) & 3) << 4))) =
            f2bf(tile[kc][nl]);
    }
}

// main: 256-thr, wave 64x32, block 128x64, BK=32, 4x20KB buffers.
// A staged in-kernel: fp32 global->reg (asm, issued early) -> cvt_pk_bf16 -> LDS.
__global__ __launch_bounds__(THREADS, 2) void augru_main(
    const float* __restrict__ x, const float* __restrict__ h,
    const float* __restrict__ att, const unsigned short* __restrict__ Wt2,
    const float* __restrict__ bu, const float* __restrict__ br,
    const float* __restrict__ bc, float* __restrict__ out) {
    extern __shared__ char smem[];   // 4 x 20 KB
    const int tid = threadIdx.x;
    const int lane = tid & 63;
    const int wid = tid >> 6;   // 0..3
    const int wm = wid >> 1;    // 0..1 -> 64-row half
    const int wn = wid & 1;     // 0..1 -> 32-col half
    const int id = blockIdx.x;
    const int wg = (id & 7) * 256 + (id >> 3);   // XCD-bijective; nb-siblings co-XCD
    const int nb = wg & 7;      // 0..7 -> 64-col block
    const int mb = wg >> 3;     // 0..255
    const int cl = lane & 15;
    const int kg = lane >> 4;

    f32x4 accU[4][2], accR[4][2], accCx[4][2], accCh[4][2];
#pragma unroll
    for (int i = 0; i < 4; ++i)
#pragma unroll
        for (int j = 0; j < 2; ++j) {
            accU[i][j] = (f32x4)(0.f);
            accR[i][j] = (f32x4)(0.f);
            accCx[i][j] = (f32x4)(0.f);
            accCh[i][j] = (f32x4)(0.f);
        }

    // LDS read bases; swizzle term is mi/ni-invariant (8*mi % 4 == 0)
    const int rowb = wm * 64 + cl;
    const int aBase = rowb * 64 + ((kg * 16) ^ (((rowb >> 1) & 3) << 4));
    const int colb = wn * 32 + cl;
    const int wBase = ABUF + colb * 64 + ((kg * 16) ^ (((colb >> 1) & 3) << 4));

    // A conversion mapping: thread -> (row, 32B-half)
    const int arow = tid >> 1;            // 0..127
    const int ap = tid & 1;               // 0..1
    const int asw = ((arow >> 1) & 3) << 4;
    const int dsA0 = arow * 64 + ((ap * 32) ^ asw);
    const int dsA1 = arow * 64 + ((ap * 32 + 16) ^ asw);
    const float* pAx = x + (size_t)(mb * 128 + arow) * 512 + ap * 16;
    const float* pAh = h + (size_t)(mb * 128 + arow) * 512 - 512 + ap * 16;

    // W staging (global_load_lds, 3 loads/thread)
    const char* gW0 = (const char*)Wt2 + ((size_t)nb * 64) * 64 + tid * 16;
    auto stageW = [&](int buf, int kt) {
        char* base = smem + buf * BUF;
        const char* gW = gW0 + (size_t)kt * (3 * 512 * 64);
#pragma unroll
        for (int t = 0; t < 3; ++t)
            load_lds_16B(gW + (size_t)t * (512 * 64),
                         base + ABUF + t * 4096 + wid * 1024);
    };

    f32x4 fa0, fa1, fa2, fa3;
    auto issueA = [&](int ktn) {
        const float* g = ((ktn < 16) ? pAx : pAh) + ktn * 32;
        asm volatile(
            "global_load_dwordx4 %0, %4, off\n\t"
            "global_load_dwordx4 %1, %4, off offset:16\n\t"
            "global_load_dwordx4 %2, %4, off offset:32\n\t"
            "global_load_dwordx4 %3, %4, off offset:48"
            : "=&v"(fa0), "=&v"(fa1), "=&v"(fa2), "=&v"(fa3)
            : "v"(g)
            : "memory");
    };

    auto cvt2 = [](float lo, float hi) {
        unsigned int r;
        asm("v_cvt_pk_bf16_f32 %0, %1, %2" : "=v"(r) : "v"(lo), "v"(hi));
        return r;
    };

    auto convertA = [&](int bufA, bool wLive) {
        if (wLive) asm volatile("s_waitcnt vmcnt(3)" ::: "memory");  // A done, newest W fly
        else       asm volatile("s_waitcnt vmcnt(0)" ::: "memory");
        __builtin_amdgcn_sched_barrier(0);   // rule 18: pin cvt after the wait
        uint4v q0, q1;
        q0.x = cvt2(fa0[0], fa0[1]); q0.y = cvt2(fa0[2], fa0[3]);
        q0.z = cvt2(fa1[0], fa1[1]); q0.w = cvt2(fa1[2], fa1[3]);
        q1.x = cvt2(fa2[0], fa2[1]); q1.y = cvt2(fa2[2], fa2[3]);
        q1.z = cvt2(fa3[0], fa3[1]); q1.w = cvt2(fa3[2], fa3[3]);
        char* base = smem + bufA * BUF;
        *(uint4v*)(base + dsA0) = q0;
        *(uint4v*)(base + dsA1) = q1;
    };

    // prologue: W(0..2) in flight; A(0) loaded, converted, written to buf0
    stageW(0, 0);
    stageW(1, 1);
    stageW(2, 2);
    issueA(0);
    convertA(0, false);   // vmcnt(0): drains W0-2 too (once, acceptable)

    auto body = [&](int kt, int buf, int bufA, f32x4(&accC)[4][2]) {
        asm volatile("s_waitcnt lgkmcnt(0)" ::: "memory");  // A ds_writes visible
        __builtin_amdgcn_s_barrier();
        const bool doA = (kt + 1 < NKT);
        const bool doW = (kt + 3 < NKT);
        if (doA) issueA(kt + 1);           // issued FIRST (vmcnt order: A older than W)
        if (doW) stageW((kt + 3) & 3, kt + 3);
        const char* aB = smem + buf * BUF;
        bf16x8 a[4], bb[3][2];
#pragma unroll
        for (int mi = 0; mi < 4; ++mi)
            a[mi] = __builtin_bit_cast(bf16x8,
                *(const uint4v*)(aB + aBase + mi * 1024));
#pragma unroll
        for (int t = 0; t < 3; ++t)
#pragma unroll
            for (int ni = 0; ni < 2; ++ni)
                bb[t][ni] = __builtin_bit_cast(bf16x8,
                    *(const uint4v*)(aB + wBase + t * 4096 + ni * 1024));
        __builtin_amdgcn_s_setprio(1);
#pragma unroll
        for (int ni = 0; ni < 2; ++ni) {
#pragma unroll
            for (int mi = 0; mi < 4; ++mi)
                accU[mi][ni] = __builtin_amdgcn_mfma_f32_16x16x32_bf16(
                    a[mi], bb[0][ni], accU[mi][ni], 0, 0, 0);
#pragma unroll
            for (int mi = 0; mi < 4; ++mi)
                accR[mi][ni] = __builtin_amdgcn_mfma_f32_16x16x32_bf16(
                    a[mi], bb[1][ni], accR[mi][ni], 0, 0, 0);
#pragma unroll
            for (int mi = 0; mi < 4; ++mi)
                accC[mi][ni] = __builtin_amdgcn_mfma_f32_16x16x32_bf16(
                    a[mi], bb[2][ni], accC[mi][ni], 0, 0, 0);
        }
        __builtin_amdgcn_s_setprio(0);
        if (doA) convertA(bufA, doW);      // hide A latency under the MFMAs above
    };

    for (int g = 0; g < 4; ++g) {          // kt 0..15: x-half -> cx
        const int k0 = g * 4;
        body(k0 + 0, 0, 1, accCx);
        body(k0 + 1, 1, 2, accCx);
        body(k0 + 2, 2, 3, accCx);
        body(k0 + 3, 3, 0, accCx);
    }
    for (int g = 4; g < 8; ++g) {          // kt 16..31: h-half -> ch
        const int k0 = g * 4;
        body(k0 + 0, 0, 1, accCh);
        body(k0 + 1, 1, 2, accCh);
        body(k0 + 2, 2, 3, accCh);
        body(k0 + 3, 3, 0, accCh);
    }

    // ---- fused epilogue ----
#pragma unroll
    for (int ni = 0; ni < 2; ++ni) {
        const int col = nb * 64 + wn * 32 + ni * 16 + cl;
        const float bU = bu[col];
        const float bR = br[col];
        const float bC = bc[col];
#pragma unroll
        for (int mi = 0; mi < 4; ++mi) {
#pragma unroll
            for (int j = 0; j < 4; ++j) {
                const int row = mb * 128 + wm * 64 + mi * 16 + kg * 4 + j;
                const float up = accU[mi][ni][j] + bU;
                const float rp = accR[mi][ni][j] + bR;
                const float u = 1.f / (1.f + __expf(-up));
                const float r = 1.f / (1.f + __expf(-rp));
                const float cpre = accCx[mi][ni][j] + bC + r * accCh[mi][ni][j];
                const float e = __expf(-2.f * cpre);
                const float cc = (1.f - e) / (1.f + e);   // tanh
                const float aa = att[row];
                const float hv = h[(size_t)row * 512 + col];
                const float u_ = aa * u;
                out[(size_t)row * 512 + col] = (1.f - u_) * hv + u_ * cc;
            }
        }
    }
}

extern "C" void kernel_launch(void* const* d_in, const int* in_sizes, int n_in,
                              void* d_out, int out_size, void* d_ws, size_t ws_size,
                              hipStream_t stream) {
    const float* x    = (const float*)d_in[0];
    const float* h    = (const float*)d_in[1];
    const float* att  = (const float*)d_in[2];
    const float* Wu_x = (const float*)d_in[3];
    const float* bu   = (const float*)d_in[4];
    const float* Wu_h = (const float*)d_in[5];
    const float* Wr_x = (const float*)d_in[6];
    const float* br   = (const float*)d_in[7];
    const float* Wr_h = (const float*)d_in[8];
    const float* Wc_x = (const float*)d_in[9];
    const float* bc   = (const float*)d_in[10];
    const float* Wc_h = (const float*)d_in[11];
    unsigned short* Wt2 = (unsigned short*)d_ws;   // 3 MB
    float* out = (float*)d_out;

    prep_weights<<<dim3(32, 16, 3), 256, 0, stream>>>(Wu_x, Wu_h, Wr_x, Wr_h, Wc_x, Wc_h, Wt2);

    hipFuncSetAttribute((const void*)augru_main,
                        hipFuncAttributeMaxDynamicSharedMemorySize, 4 * BUF);
    augru_main<<<dim3(2048), THREADS, 4 * BUF, stream>>>(
        x, h, att, Wt2, bu, br, bc, out);
}